// Round 10
// baseline (246.244 us; speedup 1.0000x reference)
//
#include <hip/hip_runtime.h>

typedef __attribute__((ext_vector_type(4))) float f32x4;
typedef __attribute__((ext_vector_type(8))) short bf16x8;
typedef unsigned short USHORT;

static __device__ __forceinline__ float bf2f(USHORT u) {
    return __uint_as_float(((unsigned)u) << 16);
}
static __device__ __forceinline__ USHORT f2bf(float f) {
    unsigned u = __float_as_uint(f);
    unsigned r = u + 0x7FFF + ((u >> 16) & 1);   // RTNE
    return (USHORT)(r >> 16);
}

#define GLDS16(gp, lp) __builtin_amdgcn_global_load_lds(                      \
    (const __attribute__((address_space(1))) unsigned int*)(gp),              \
    (__attribute__((address_space(3))) unsigned int*)(lp), 16, 0, 0)

#define FULL_BARRIER() asm volatile("s_waitcnt vmcnt(0) lgkmcnt(0)\ns_barrier" ::: "memory")

#define D64 0.52559648f            // 0.99^64
#define L2D (-0.014499569695115089f) // log2(0.99)

// ---------------------------------------------------------------------------
__global__ __launch_bounds__(256) void k_cast_x(const float* __restrict__ x,
                                                USHORT* __restrict__ xb) {
    const int i = (blockIdx.x * 256 + threadIdx.x) * 4;
    float4 v = *(const float4*)&x[i];
    *(ushort4*)&xb[i] = make_ushort4(f2bf(v.x), f2bf(v.y), f2bf(v.z), f2bf(v.w));
}

// ---------------------------------------------------------------------------
struct TWArgs { const float* src[5]; USHORT* dst[5]; };

__global__ __launch_bounds__(256) void k_transpose_w(TWArgs ta) {
    const float* __restrict__ W  = ta.src[blockIdx.z];
    USHORT* __restrict__      WT = ta.dst[blockIdx.z];
    __shared__ USHORT t[64][65];
    const int k0 = blockIdx.y * 64, n0 = blockIdx.x * 64;
    const int tid = threadIdx.x;
#pragma unroll
    for (int s = 0; s < 4; s++) {
        int slot = tid + s * 256;
        int row = slot >> 4, c4 = (slot & 15) * 4;
        float4 vv = *(const float4*)&W[(size_t)(k0 + row) * 1024 + n0 + c4];
        t[row][c4 + 0] = f2bf(vv.x);
        t[row][c4 + 1] = f2bf(vv.y);
        t[row][c4 + 2] = f2bf(vv.z);
        t[row][c4 + 3] = f2bf(vv.w);
    }
    __syncthreads();
#pragma unroll
    for (int s = 0; s < 2; s++) {
        int slot = tid + s * 256;
        int n = slot >> 3, c8 = (slot & 7) * 8;
        USHORT tmp[8];
#pragma unroll
        for (int u = 0; u < 8; u++) tmp[u] = t[c8 + u][n];
        *(int4*)&WT[(size_t)(n0 + n) * 1024 + k0 + c8] = *(int4*)tmp;
    }
}

// ---------------------------------------------------------------------------
// GEMM with glds double-buffer. A bf16 (glds) or fp32 (VALU-convert staging).
// mode 0: bf16 store; 1: sigmoid bf16; 2: V->VT[b,h,d,s] * 0.99^{-(s&63)};
// mode 3: fp32 store; mode 4: bf16 store * scale * 0.99^{(row&63)} (Q'').
// ---------------------------------------------------------------------------
struct GArgs {
    const void*   A;
    int           a_fp32;
    const USHORT* W[4];
    const float*  bias[4];
    void*         dst[4];
    USHORT*       dstv;
    float         scale[4];
    int           mode[4];
};

__global__ __launch_bounds__(256, 2) void k_gemm(GArgs ga) {
    const int z = blockIdx.z;
    const USHORT* __restrict__ BT = ga.W[z];
    __shared__ USHORT As[2][128 * 32];
    __shared__ USHORT Bs[2][128 * 32];
    const int tid = threadIdx.x;
    const int m0 = blockIdx.y * 128, n0 = blockIdx.x * 128;
    const int w = tid >> 6, l = tid & 63, lr = l & 15, q = l >> 4;
    const int wr = w >> 1, wc = w & 1;
    const int srow = tid >> 2, sco = (tid & 3) * 8;
    f32x4 acc[4][4] = {};
    // stage tile 0 into buffer 0
    if (ga.a_fp32) {
        const float* Af = (const float*)ga.A;
#pragma unroll
        for (int hrow = 0; hrow < 2; hrow++) {
            float4 f0 = *(const float4*)&Af[(size_t)(m0 + srow + hrow * 64) * 1024 + sco];
            float4 f1 = *(const float4*)&Af[(size_t)(m0 + srow + hrow * 64) * 1024 + sco + 4];
            USHORT a8[8];
            a8[0]=f2bf(f0.x); a8[1]=f2bf(f0.y); a8[2]=f2bf(f0.z); a8[3]=f2bf(f0.w);
            a8[4]=f2bf(f1.x); a8[5]=f2bf(f1.y); a8[6]=f2bf(f1.z); a8[7]=f2bf(f1.w);
            *(int4*)&As[0][(srow + hrow * 64) * 32 + sco] = *(int4*)a8;
        }
    } else {
        const USHORT* Ab = (const USHORT*)ga.A;
        GLDS16(&Ab[(size_t)(m0 + srow)      * 1024 + sco], &As[0][srow * 32 + sco]);
        GLDS16(&Ab[(size_t)(m0 + srow + 64) * 1024 + sco], &As[0][(srow + 64) * 32 + sco]);
    }
    GLDS16(&BT[(size_t)(n0 + srow)      * 1024 + sco], &Bs[0][srow * 32 + sco]);
    GLDS16(&BT[(size_t)(n0 + srow + 64) * 1024 + sco], &Bs[0][(srow + 64) * 32 + sco]);
    for (int kt = 0; kt < 32; kt++) {
        const int cur = kt & 1;
        FULL_BARRIER();
        if (kt + 1 < 32) {
            const int k1 = (kt + 1) * 32;
            const int nxt = 1 - cur;
            if (ga.a_fp32) {
                const float* Af = (const float*)ga.A;
#pragma unroll
                for (int hrow = 0; hrow < 2; hrow++) {
                    float4 f0 = *(const float4*)&Af[(size_t)(m0 + srow + hrow * 64) * 1024 + k1 + sco];
                    float4 f1 = *(const float4*)&Af[(size_t)(m0 + srow + hrow * 64) * 1024 + k1 + sco + 4];
                    USHORT a8[8];
                    a8[0]=f2bf(f0.x); a8[1]=f2bf(f0.y); a8[2]=f2bf(f0.z); a8[3]=f2bf(f0.w);
                    a8[4]=f2bf(f1.x); a8[5]=f2bf(f1.y); a8[6]=f2bf(f1.z); a8[7]=f2bf(f1.w);
                    *(int4*)&As[nxt][(srow + hrow * 64) * 32 + sco] = *(int4*)a8;
                }
            } else {
                const USHORT* Ab = (const USHORT*)ga.A;
                GLDS16(&Ab[(size_t)(m0 + srow)      * 1024 + k1 + sco], &As[nxt][srow * 32 + sco]);
                GLDS16(&Ab[(size_t)(m0 + srow + 64) * 1024 + k1 + sco], &As[nxt][(srow + 64) * 32 + sco]);
            }
            GLDS16(&BT[(size_t)(n0 + srow)      * 1024 + k1 + sco], &Bs[nxt][srow * 32 + sco]);
            GLDS16(&BT[(size_t)(n0 + srow + 64) * 1024 + k1 + sco], &Bs[nxt][(srow + 64) * 32 + sco]);
        }
        bf16x8 af[4], bfr[4];
#pragma unroll
        for (int mi = 0; mi < 4; mi++)
            af[mi] = *(const bf16x8*)&As[cur][(wr * 64 + mi * 16 + lr) * 32 + q * 8];
#pragma unroll
        for (int ni = 0; ni < 4; ni++)
            bfr[ni] = *(const bf16x8*)&Bs[cur][(wc * 64 + ni * 16 + lr) * 32 + q * 8];
#pragma unroll
        for (int mi = 0; mi < 4; mi++)
#pragma unroll
            for (int ni = 0; ni < 4; ni++)
                acc[mi][ni] = __builtin_amdgcn_mfma_f32_16x16x32_bf16(
                    af[mi], bfr[ni], acc[mi][ni], 0, 0, 0);
    }
    const float scale = ga.scale[z];
    const int mode = ga.mode[z];
    const float* __restrict__ bias = ga.bias[z];
#pragma unroll
    for (int ni = 0; ni < 4; ni++) {
        int col = n0 + wc * 64 + ni * 16 + lr;          // D col = lane&15
        float bv = bias[col];
#pragma unroll
        for (int mi = 0; mi < 4; mi++) {
            int r0 = m0 + wr * 64 + mi * 16 + q * 4;    // D row = quad*4+reg
            float vr[4];
#pragma unroll
            for (int r = 0; r < 4; r++) {
                float v = acc[mi][ni][r] + bv;
                if (mode == 1) v = 1.0f / (1.0f + __expf(-v));
                vr[r] = v * scale;
            }
            if (mode == 4) {
                // Q'': extra row decay 0.99^{(s&63)}  (s = r0+r, r0%4==0)
                float d0 = exp2f(L2D * (float)(r0 & 63));
                vr[0] *= d0;
                vr[1] *= d0 * 0.99f;
                vr[2] *= d0 * 0.9801f;
                vr[3] *= d0 * 0.970299f;
            }
            if (mode == 3) {
                float* df = (float*)ga.dst[z];
#pragma unroll
                for (int r = 0; r < 4; r++)
                    df[(size_t)(r0 + r) * 1024 + col] = vr[r];
            } else if (mode == 2) {
                int b = r0 >> 11, s = r0 & 2047;
                int h = col >> 6, d = col & 63;
                const float NP1 = 1.0101010101010102f;          // 0.99^-1
                float c0 = exp2f(-L2D * (float)(s & 63));
                float c1 = c0 * NP1, c2 = c1 * NP1, c3 = c2 * NP1;
                *(ushort4*)&ga.dstv[(size_t)(((b * 16 + h) * 64) + d) * 2048 + s] =
                    make_ushort4(f2bf(vr[0] * c0), f2bf(vr[1] * c1),
                                 f2bf(vr[2] * c2), f2bf(vr[3] * c3));
            } else {
                USHORT* db = (USHORT*)ga.dst[z];
#pragma unroll
                for (int r = 0; r < 4; r++)
                    db[(size_t)(r0 + r) * 1024 + col] = f2bf(vr[r]);
            }
        }
    }
}

// ---------------------------------------------------------------------------
// U_c = 0.99^64 * V'_c^T @ K_c  stored as UT[dv][dk] fp32 at slot (bh,c).
// grid (32 bh, 32 c). K transposed in LDS; VT staged directly.
// ---------------------------------------------------------------------------
__global__ __launch_bounds__(256) void k_attn_u(const USHORT* __restrict__ K,
                                                const USHORT* __restrict__ VT,
                                                float* __restrict__ Sst) {
    const int bh = blockIdx.x, c = blockIdx.y;
    const int b = bh >> 4, h = bh & 15;
    const int tid = threadIdx.x, w = tid >> 6, l = tid & 63, lr = l & 15, q = l >> 4;
    __shared__ USHORT KT[64 * 72];
    __shared__ USHORT Vs[64 * 72];
#pragma unroll
    for (int s = 0; s < 2; s++) {
        int slot = tid + s * 256;
        int row = slot >> 3, co = (slot & 7) * 8;
        USHORT kv[8];
        *(int4*)kv = *(const int4*)&K[(size_t)(b * 2048 + c * 64 + row) * 1024 + h * 64 + co];
#pragma unroll
        for (int u = 0; u < 8; u++) KT[(co + u) * 72 + row] = kv[u];
        *(int4*)&Vs[row * 72 + co] =
            *(const int4*)&VT[(size_t)(bh * 64 + row) * 2048 + c * 64 + co];
    }
    __syncthreads();
    // wave w: dv rows w*16..+15; D[dv][dk] over 4 dk-tiles, contraction s=64.
    f32x4 acc[4] = {};
    bf16x8 av[2];
#pragma unroll
    for (int kk = 0; kk < 2; kk++)
        av[kk] = *(const bf16x8*)&Vs[(w * 16 + lr) * 72 + kk * 32 + q * 8];
#pragma unroll
    for (int dkt = 0; dkt < 4; dkt++)
#pragma unroll
        for (int kk = 0; kk < 2; kk++) {
            bf16x8 bk = *(const bf16x8*)&KT[(dkt * 16 + lr) * 72 + kk * 32 + q * 8];
            acc[dkt] = __builtin_amdgcn_mfma_f32_16x16x32_bf16(av[kk], bk, acc[dkt], 0, 0, 0);
        }
    float* slot = Sst + (size_t)(bh * 32 + c) * 4096;
#pragma unroll
    for (int dkt = 0; dkt < 4; dkt++)
#pragma unroll
        for (int r = 0; r < 4; r++)
            slot[(w * 16 + q * 4 + r) * 64 + dkt * 16 + lr] = acc[dkt][r] * D64;
}

// ---------------------------------------------------------------------------
// In-place scan: S_{c+1} = 0.99^64 * S_c + U_c ; slot c <- S_{c+1} packed
// (hi bf16 low16, lo bf16 high16). grid (32 bh, 4 dv-groups of 16).
// ---------------------------------------------------------------------------
__global__ __launch_bounds__(256) void k_scan(float* __restrict__ Sst) {
    const int bh = blockIdx.x, dvg = blockIdx.y;
    const int tid = threadIdx.x;
    const int dv = dvg * 16 + (tid >> 4), dk4 = (tid & 15) * 4;
    float s0 = 0.f, s1 = 0.f, s2 = 0.f, s3 = 0.f;
    for (int c = 0; c < 32; c++) {
        float* p = Sst + (size_t)(bh * 32 + c) * 4096 + dv * 64 + dk4;
        float4 u = *(const float4*)p;
        s0 = s0 * D64 + u.x; s1 = s1 * D64 + u.y;
        s2 = s2 * D64 + u.z; s3 = s3 * D64 + u.w;
        unsigned pk[4];
        float sv[4] = { s0, s1, s2, s3 };
#pragma unroll
        for (int r = 0; r < 4; r++) {
            USHORT hi = f2bf(sv[r]);
            float  lo = sv[r] - bf2f(hi);
            pk[r] = (unsigned)hi | ((unsigned)f2bf(lo) << 16);
        }
        *(uint4*)p = make_uint4(pk[0], pk[1], pk[2], pk[3]);
    }
}

// ---------------------------------------------------------------------------
// Attention apply: per (bh, 128-i-block): diag 64x64 masked tile (decay fully
// pre-folded into Q'' and V') + cross via state S_c (hi/lo bf16 MFMA pair).
// Wave w: 32 i rows, chunk c = iw0>>6. Uniform work, no atomics.
// ---------------------------------------------------------------------------
__global__ __launch_bounds__(256, 2) void k_attn(const USHORT* __restrict__ Q,
                                                 const USHORT* __restrict__ K,
                                                 const USHORT* __restrict__ VT,
                                                 const float* __restrict__ Sst,
                                                 float* __restrict__ R) {
    const int bh = blockIdx.x;
    const int b = bh >> 4, h = bh & 15;
    const int i0 = blockIdx.y * 128;
    const int tid = threadIdx.x, w = tid >> 6, l = tid & 63, lr = l & 15, q = l >> 4;
    __shared__ USHORT Qs[128 * 72];
    __shared__ USHORT Ks[128 * 72];
    __shared__ USHORT Vs[64 * 136];
    __shared__ USHORT Ps[4][32 * 72];
#pragma unroll
    for (int s = 0; s < 4; s++) {
        int slot = tid + s * 256;
        int rw = slot >> 3, c8 = (slot & 7) * 8;
        *(int4*)&Qs[rw * 72 + c8] =
            *(const int4*)&Q[(size_t)(b * 2048 + i0 + rw) * 1024 + h * 64 + c8];
        *(int4*)&Ks[rw * 72 + c8] =
            *(const int4*)&K[(size_t)(b * 2048 + i0 + rw) * 1024 + h * 64 + c8];
    }
#pragma unroll
    for (int s = 0; s < 4; s++) {
        int slot = tid + s * 256;
        int rw = slot >> 4, co = (slot & 15) * 8;   // 64 rows x 128 cols
        *(int4*)&Vs[rw * 136 + co] =
            *(const int4*)&VT[(size_t)(bh * 64 + rw) * 2048 + i0 + co];
    }
    __syncthreads();
    const int iw0 = i0 + w * 32;
    const int cglob = iw0 >> 6;          // this wave's chunk
    const int cw = w >> 1;               // chunk within block (0/1)
    // Q'' fragments (used by diag and cross)
    bf16x8 bqf[2][2];
#pragma unroll
    for (int kk = 0; kk < 2; kk++)
#pragma unroll
        for (int it = 0; it < 2; it++)
            bqf[kk][it] = *(const bf16x8*)&Qs[(w * 32 + it * 16 + lr) * 72 + kk * 32 + q * 8];
    f32x4 accr[4][2] = {};
    // ---- cross: out^T += S_c^T @ Q''  (skip chunk 0) ----
    if (cglob >= 1) {
        const unsigned* Sb = (const unsigned*)(Sst + (size_t)(bh * 32 + cglob - 1) * 4096);
#pragma unroll
        for (int dt = 0; dt < 4; dt++)
#pragma unroll
            for (int kk = 0; kk < 2; kk++) {
                const unsigned* p = Sb + (dt * 16 + lr) * 64 + kk * 32 + q * 8;
                uint4 pa = *(const uint4*)p;
                uint4 pb = *(const uint4*)(p + 4);
                unsigned pk[8] = { pa.x, pa.y, pa.z, pa.w, pb.x, pb.y, pb.z, pb.w };
                bf16x8 hi, lo;
#pragma unroll
                for (int u = 0; u < 8; u++) {
                    hi[u] = (short)(pk[u] & 0xffffu);
                    lo[u] = (short)(pk[u] >> 16);
                }
#pragma unroll
                for (int it = 0; it < 2; it++) {
                    accr[dt][it] = __builtin_amdgcn_mfma_f32_16x16x32_bf16(
                        hi, bqf[kk][it], accr[dt][it], 0, 0, 0);
                    accr[dt][it] = __builtin_amdgcn_mfma_f32_16x16x32_bf16(
                        lo, bqf[kk][it], accr[dt][it], 0, 0, 0);
                }
            }
    }
    // ---- diag: P^T = K_c @ Q''^T, mask j<=i, pack bf16, PV with V' ----
    {
        const int j0 = cglob * 64;
        f32x4 accp[4][2] = {};
#pragma unroll
        for (int kk = 0; kk < 2; kk++)
#pragma unroll
            for (int jt = 0; jt < 4; jt++) {
                bf16x8 akf = *(const bf16x8*)&Ks[(cw * 64 + jt * 16 + lr) * 72 + kk * 32 + q * 8];
#pragma unroll
                for (int it = 0; it < 2; it++)
                    accp[jt][it] = __builtin_amdgcn_mfma_f32_16x16x32_bf16(
                        akf, bqf[kk][it], accp[jt][it], 0, 0, 0);
            }
#pragma unroll
        for (int jt = 0; jt < 4; jt++)
#pragma unroll
            for (int it = 0; it < 2; it++) {
                const int ii = iw0 + it * 16 + lr;
                const int jj = j0 + jt * 16 + q * 4;
                float v0 = (jj + 0 <= ii) ? accp[jt][it][0] : 0.0f;
                float v1 = (jj + 1 <= ii) ? accp[jt][it][1] : 0.0f;
                float v2 = (jj + 2 <= ii) ? accp[jt][it][2] : 0.0f;
                float v3 = (jj + 3 <= ii) ? accp[jt][it][3] : 0.0f;
                unsigned w0 = __builtin_amdgcn_perm(
                    __float_as_uint(v1), __float_as_uint(v0), 0x07060302u);
                unsigned w1 = __builtin_amdgcn_perm(
                    __float_as_uint(v3), __float_as_uint(v2), 0x07060302u);
                *(uint2*)&Ps[w][(it * 16 + lr) * 72 + jt * 16 + q * 4] = make_uint2(w0, w1);
            }
        asm volatile("s_waitcnt lgkmcnt(0)" ::: "memory");
#pragma unroll
        for (int kk = 0; kk < 2; kk++) {
            bf16x8 bpf[2];
#pragma unroll
            for (int it = 0; it < 2; it++)
                bpf[it] = *(const bf16x8*)&Ps[w][(it * 16 + lr) * 72 + kk * 32 + q * 8];
#pragma unroll
            for (int dt = 0; dt < 4; dt++) {
                bf16x8 avf = *(const bf16x8*)&Vs[(dt * 16 + lr) * 136 + cw * 64 + kk * 32 + q * 8];
#pragma unroll
                for (int it = 0; it < 2; it++)
                    accr[dt][it] = __builtin_amdgcn_mfma_f32_16x16x32_bf16(
                        avf, bpf[it], accr[dt][it], 0, 0, 0);
            }
        }
    }
#pragma unroll
    for (int it = 0; it < 2; it++) {
        int i = i0 + w * 32 + it * 16 + lr;
#pragma unroll
        for (int dt = 0; dt < 4; dt++) {
            *(f32x4*)&R[(size_t)(b * 2048 + i) * 1024 + h * 64 + dt * 16 + q * 4] =
                accr[dt][it];
        }
    }
}

// ---------------------------------------------------------------------------
__global__ __launch_bounds__(256) void k_ln_gate(const float* __restrict__ R,
                                                 const USHORT* __restrict__ G,
                                                 const float* __restrict__ gamma,
                                                 const float* __restrict__ beta,
                                                 USHORT* __restrict__ NG) {
    const int row = blockIdx.x, tid = threadIdx.x;
    const float4 v = *(const float4*)&R[(size_t)row * 1024 + tid * 4];
    float vv[4] = { v.x, v.y, v.z, v.w };
    float s  = vv[0] + vv[1] + vv[2] + vv[3];
    float s2 = vv[0]*vv[0] + vv[1]*vv[1] + vv[2]*vv[2] + vv[3]*vv[3];
#pragma unroll
    for (int o = 32; o > 0; o >>= 1) {
        s  += __shfl_down(s, o, 64);
        s2 += __shfl_down(s2, o, 64);
    }
    __shared__ float red[8];
    if ((tid & 63) == 0) { red[tid >> 6] = s; red[4 + (tid >> 6)] = s2; }
    __syncthreads();
    const float ts  = red[0] + red[1] + red[2] + red[3];
    const float ts2 = red[4] + red[5] + red[6] + red[7];
    const float mu  = ts * (1.0f / 1024.0f);
    const float var = ts2 * (1.0f / 1024.0f) - mu * mu;
    const float inv = rsqrtf(var + 1e-5f);
    ushort4 g4 = *(const ushort4*)&G[(size_t)row * 1024 + tid * 4];
    float4 gm = *(const float4*)&gamma[tid * 4];
    float4 bt = *(const float4*)&beta[tid * 4];
    USHORT gg[4]  = { g4.x, g4.y, g4.z, g4.w };
    float  gmm[4] = { gm.x, gm.y, gm.z, gm.w };
    float  btt[4] = { bt.x, bt.y, bt.z, bt.w };
    USHORT o4[4];
#pragma unroll
    for (int u = 0; u < 4; u++) {
        float nv = (vv[u] - mu) * inv * gmm[u] + btt[u];
        o4[u] = f2bf(nv * bf2f(gg[u]));
    }
    *(ushort4*)&NG[(size_t)row * 1024 + tid * 4] = make_ushort4(o4[0], o4[1], o4[2], o4[3]);
}

// ---------------------------------------------------------------------------
extern "C" void kernel_launch(void* const* d_in, const int* in_sizes, int n_in,
                              void* d_out, int out_size, void* d_ws, size_t ws_size,
                              hipStream_t stream) {
    const float* x     = (const float*)d_in[0];
    const float* Wq    = (const float*)d_in[1];
    const float* bq    = (const float*)d_in[2];
    const float* Wk    = (const float*)d_in[3];
    const float* bk    = (const float*)d_in[4];
    const float* Wv    = (const float*)d_in[5];
    const float* bv    = (const float*)d_in[6];
    const float* Wg    = (const float*)d_in[7];
    const float* bg    = (const float*)d_in[8];
    const float* Wo    = (const float*)d_in[9];
    const float* bo    = (const float*)d_in[10];
    const float* gamma = (const float*)d_in[11];
    const float* beta  = (const float*)d_in[12];

    // ws layout (50 MB total):
    // 0-10: WT x5 | 10-18: Qb(Q'') -> later Gb | 18-26: Kb -> later NGb
    // 26-34: VTb | 34-50: U/S state slots (fp32, 32bh x 32c x 64x64)
    char* ws = (char*)d_ws;
    const size_t MB = 1 << 20;
    USHORT* WqT = (USHORT*)(ws + 0 * MB);
    USHORT* WkT = (USHORT*)(ws + 2 * MB);
    USHORT* WvT = (USHORT*)(ws + 4 * MB);
    USHORT* WgT = (USHORT*)(ws + 6 * MB);
    USHORT* WoT = (USHORT*)(ws + 8 * MB);
    USHORT* Qb  = (USHORT*)(ws + 10 * MB);
    USHORT* Kb  = (USHORT*)(ws + 18 * MB);
    USHORT* VTb = (USHORT*)(ws + 26 * MB);
    float*  Sst = (float*) (ws + 34 * MB);
    USHORT* Gb  = Qb;                 // Q'' dead after attn
    USHORT* NGb = Kb;                 // Kb dead after attn
    USHORT* Xb  = (USHORT*)d_out;     // bf16 x (8 MB), dead after Q/K/V proj
    float*  Rf  = (float*)d_out;      // fp32 retained (16 MB)

    k_cast_x<<<4096, 256, 0, stream>>>(x, Xb);
    {
        TWArgs ta;
        ta.src[0] = Wq; ta.src[1] = Wk; ta.src[2] = Wv; ta.src[3] = Wg; ta.src[4] = Wo;
        ta.dst[0] = WqT; ta.dst[1] = WkT; ta.dst[2] = WvT; ta.dst[3] = WgT; ta.dst[4] = WoT;
        k_transpose_w<<<dim3(16, 16, 5), 256, 0, stream>>>(ta);
    }
    {   // Q'' (mode 4, 1/8 * row decay), K (mode 0), V (mode 2: VT + col decay)
        GArgs ga;
        ga.A = Xb; ga.a_fp32 = 0;
        ga.W[0] = WqT; ga.W[1] = WkT; ga.W[2] = WvT; ga.W[3] = WvT;
        ga.bias[0] = bq; ga.bias[1] = bk; ga.bias[2] = bv; ga.bias[3] = bv;
        ga.dst[0] = Qb; ga.dst[1] = Kb; ga.dst[2] = nullptr; ga.dst[3] = nullptr;
        ga.dstv = VTb;
        ga.scale[0] = 0.125f; ga.scale[1] = 1.0f; ga.scale[2] = 1.0f; ga.scale[3] = 1.0f;
        ga.mode[0] = 4; ga.mode[1] = 0; ga.mode[2] = 2; ga.mode[3] = 2;
        k_gemm<<<dim3(8, 32, 3), 256, 0, stream>>>(ga);
    }
    k_attn_u<<<dim3(32, 32), 256, 0, stream>>>(Kb, VTb, Sst);
    k_scan<<<dim3(32, 4), 256, 0, stream>>>(Sst);
    k_attn<<<dim3(32, 16), 256, 0, stream>>>(Qb, Kb, VTb, Sst, Rf);
    {   // G projection (after attn; fp32 A staging from x) -> Gb (= old Qb)
        GArgs gg;
        gg.A = (const void*)x; gg.a_fp32 = 1;
        for (int i = 0; i < 4; i++) {
            gg.W[i] = WgT; gg.bias[i] = bg; gg.dst[i] = Gb;
            gg.scale[i] = 1.0f; gg.mode[i] = 1;
        }
        gg.dstv = nullptr;
        k_gemm<<<dim3(8, 32, 1), 256, 0, stream>>>(gg);
    }
    k_ln_gate<<<4096, 256, 0, stream>>>(Rf, Gb, gamma, beta, NGb);
    {   // output projection -> d_out fp32 (mode 3)
        GArgs go;
        go.A = NGb; go.a_fp32 = 0;
        for (int i = 0; i < 4; i++) {
            go.W[i] = WoT; go.bias[i] = bo; go.dst[i] = d_out;
            go.scale[i] = 1.0f; go.mode[i] = 3;
        }
        go.dstv = nullptr;
        k_gemm<<<dim3(8, 32, 1), 256, 0, stream>>>(go);
    }
}